// Round 6
// baseline (71.014 us; speedup 1.0000x reference)
//
#include <hip/hip_runtime.h>
#include <math.h>

// MACE equivariant score head — ONE kernel + device-scope spin barriers.
// Dead code: Wss (d_in[5]), Wvv (d_in[7]) — s3=silu(s2) is deleted in the reference.
// out[n,m] = sum_c vraw[n,c,m] * h[n,c]
// h[n,c]   = t[n]*b[c] + sum_q feat[n,q] * M[q,c]
//   D[u,v] = dot(Wsv[u,v,:], W2)
//   F[q,v] = sum_u wrow[u] * D[u,v]   (wrow = W1s row 16+q, or Wt-combo for b)
//   M[q,c] = scale * sum_v F[q,v] * W1v[c,v],  scale = 1/(S*V*sqrt(V))
//
// Safety of the non-cooperative grid barrier: grid = 256 blocks (= #CUs),
// 256 threads, 75 KB LDS -> every CU hosts >=1 block under any packing
// (2x75KB <= 160KB even if two land on one CU), so all blocks are
// co-resident and the spin cannot deadlock. Counter is memset to 0 at the
// start of every kernel_launch (captured in the graph), so replays are safe.

#define S 144
#define V 128

__device__ inline void grid_barrier(unsigned* cnt, unsigned target, int tid) {
    __syncthreads();                       // drains vmcnt -> all stores issued
    if (tid == 0) {
        __threadfence();                   // agent-scope release (L2 writeback)
        __hip_atomic_fetch_add(cnt, 1u, __ATOMIC_ACQ_REL, __HIP_MEMORY_SCOPE_AGENT);
        while (__hip_atomic_load(cnt, __ATOMIC_ACQUIRE, __HIP_MEMORY_SCOPE_AGENT) < target)
            __builtin_amdgcn_s_sleep(2);
        __threadfence();                   // agent-scope acquire (inv stale lines)
    }
    __syncthreads();
}

__global__ __launch_bounds__(256) void fused_mace(
        const float* __restrict__ feat,   // [4096,512]
        const float* __restrict__ times,  // [4096,1]
        const float* __restrict__ Wt,     // [1,16]
        const float* __restrict__ W1s,    // [144,144]
        const float* __restrict__ W1v,    // [128,128]
        const float* __restrict__ Wsv,    // [144,128,128]
        const float* __restrict__ W2,     // [128,1]
        float* __restrict__ D,            // ws
        float* __restrict__ M,            // ws
        float* __restrict__ bvec,         // ws
        unsigned* __restrict__ cnt,       // ws (memset to 0 per launch)
        float* __restrict__ out) {        // [4096,3]
    __shared__ float Msh[V * V];          // 64 KB  (phase 3)
    __shared__ float srow[4][4][V];       // 8 KB   (phase 0 -> phase 3)
    __shared__ float wrow[S];             // phase 2
    __shared__ float Fpart[4][V];         // phase 2
    __shared__ float Fsh[V];              // phase 2

    const int tid = threadIdx.x;
    const int wave = tid >> 6;
    const int lane = tid & 63;
    const int n0 = blockIdx.x * 16 + wave * 4;

    // ---------- phase 0: issue this block's feat/time loads ----------
    float2 va[4][3];
#pragma unroll
    for (int r = 0; r < 4; ++r) {
        const float* p = feat + (size_t)(n0 + r) * 512 + V + 6 * lane;
        va[r][0] = *(const float2*)(p + 0);
        va[r][1] = *(const float2*)(p + 2);
        va[r][2] = *(const float2*)(p + 4);
    }
    float2 sv[4];
#pragma unroll
    for (int r = 0; r < 4; ++r)
        sv[r] = *(const float2*)(feat + (size_t)(n0 + r) * 512 + 2 * lane);
    float tval[4];
#pragma unroll
    for (int r = 0; r < 4; ++r) tval[r] = times[n0 + r];

    // ---------- phase 1: D rows (72 per block, 18 per wave) ----------
    const int uv0 = blockIdx.x * 72 + wave * 18;
    const float2 w2v = ((const float2*)W2)[lane];
    float2 a[18];
#pragma unroll
    for (int i = 0; i < 18; ++i)
        a[i] = ((const float2*)Wsv)[(size_t)(uv0 + i) * 64 + lane];

    // park scalar rows in LDS while Wsv loads are in flight
#pragma unroll
    for (int r = 0; r < 4; ++r)
        *(float2*)&srow[wave][r][2 * lane] = sv[r];

#pragma unroll
    for (int i = 0; i < 18; ++i) {
        float acc = a[i].x * w2v.x + a[i].y * w2v.y;
#pragma unroll
        for (int off = 1; off < 64; off <<= 1)
            acc += __shfl_xor(acc, off, 64);
        if (lane == 0) D[uv0 + i] = acc;
    }

    grid_barrier(cnt, 256, tid);

    // ---------- phase 2: rows of M (blocks 0..127) and b (block 128) ----------
    if (blockIdx.x < 129) {
        const int q = blockIdx.x;
        if (tid < S) {
            if (q < V) {
                wrow[tid] = W1s[(16 + q) * S + tid];
            } else {
                float acc = 0.f;
#pragma unroll
                for (int p = 0; p < 16; ++p)
                    acc = fmaf(Wt[p], W1s[p * S + tid], acc);
                wrow[tid] = acc;
            }
        }
        __syncthreads();
        // F[v] = sum_u wrow[u]*D[u,v]; wave w: u in [36w,36w+36), lane t -> v=2t,2t+1
        {
            const int w = tid >> 6, t = tid & 63;
            float fx = 0.f, fy = 0.f;
#pragma unroll 6
            for (int u = 36 * w; u < 36 * w + 36; ++u) {
                const float wr = wrow[u];
                const float2 dv = *(const float2*)&D[u * V + 2 * t];
                fx = fmaf(wr, dv.x, fx);
                fy = fmaf(wr, dv.y, fy);
            }
            Fpart[w][2 * t + 0] = fx;
            Fpart[w][2 * t + 1] = fy;
        }
        __syncthreads();
        if (tid < V)
            Fsh[tid] = (Fpart[0][tid] + Fpart[1][tid]) + (Fpart[2][tid] + Fpart[3][tid]);
        __syncthreads();
        if (tid < V) {
            const float scale = 1.0f / (144.0f * 128.0f * sqrtf(128.0f));
            const float4* w1v4 = (const float4*)(W1v + (size_t)tid * V);
            const float4* f4 = (const float4*)Fsh;
            float m0 = 0.f, m1 = 0.f, m2 = 0.f, m3 = 0.f;
#pragma unroll
            for (int i = 0; i < V / 4; ++i) {
                const float4 wv = w1v4[i];
                const float4 fv = f4[i];
                m0 = fmaf(fv.x, wv.x, m0);
                m1 = fmaf(fv.y, wv.y, m1);
                m2 = fmaf(fv.z, wv.z, m2);
                m3 = fmaf(fv.w, wv.w, m3);
            }
            const float r = ((m0 + m1) + (m2 + m3)) * scale;
            if (q < V) M[q * V + tid] = r;
            else       bvec[tid] = r;
        }
    }

    grid_barrier(cnt, 512, tid);

    // ---------- phase 3: h = t*b + s.M, then epilogue ----------
    {
        const float4* src = (const float4*)M;
        float4* dst = (float4*)Msh;
#pragma unroll
        for (int i = 0; i < 16; ++i)
            dst[tid + 256 * i] = src[tid + 256 * i];
    }
    const float2 b2 = *(const float2*)(bvec + 2 * lane);
    float h0[4], h1[4];
#pragma unroll
    for (int r = 0; r < 4; ++r) {
        h0[r] = tval[r] * b2.x;
        h1[r] = tval[r] * b2.y;
    }
    __syncthreads();

#pragma unroll 4
    for (int q4 = 0; q4 < V / 4; ++q4) {
        const float4 s0 = *(const float4*)&srow[wave][0][q4 * 4];
        const float4 s1 = *(const float4*)&srow[wave][1][q4 * 4];
        const float4 s2 = *(const float4*)&srow[wave][2][q4 * 4];
        const float4 s3 = *(const float4*)&srow[wave][3][q4 * 4];
        const float se[4][4] = {{s0.x, s0.y, s0.z, s0.w},
                                {s1.x, s1.y, s1.z, s1.w},
                                {s2.x, s2.y, s2.z, s2.w},
                                {s3.x, s3.y, s3.z, s3.w}};
#pragma unroll
        for (int j = 0; j < 4; ++j) {
            const float2 m2 = *(const float2*)&Msh[(q4 * 4 + j) * V + 2 * lane];
#pragma unroll
            for (int r = 0; r < 4; ++r) {
                h0[r] = fmaf(se[r][j], m2.x, h0[r]);
                h1[r] = fmaf(se[r][j], m2.y, h1[r]);
            }
        }
    }

    // epilogue: lane l holds channels c=2l (va[0].x, va[0].y, va[1].x)
    // and c=2l+1 (va[1].y, va[2].x, va[2].y)
#pragma unroll
    for (int r = 0; r < 4; ++r) {
        float pm0 = va[r][0].x * h0[r] + va[r][1].y * h1[r];
        float pm1 = va[r][0].y * h0[r] + va[r][2].x * h1[r];
        float pm2 = va[r][1].x * h0[r] + va[r][2].y * h1[r];
#pragma unroll
        for (int off = 1; off < 64; off <<= 1) {
            pm0 += __shfl_xor(pm0, off, 64);
            pm1 += __shfl_xor(pm1, off, 64);
            pm2 += __shfl_xor(pm2, off, 64);
        }
        if (lane == 0) {
            out[(n0 + r) * 3 + 0] = pm0;
            out[(n0 + r) * 3 + 1] = pm1;
            out[(n0 + r) * 3 + 2] = pm2;
        }
    }
}

extern "C" void kernel_launch(void* const* d_in, const int* in_sizes, int n_in,
                              void* d_out, int out_size, void* d_ws, size_t ws_size,
                              hipStream_t stream) {
    const float* feat  = (const float*)d_in[0];
    const float* times = (const float*)d_in[1];
    const float* Wt    = (const float*)d_in[2];
    const float* W1s   = (const float*)d_in[3];
    const float* W1v   = (const float*)d_in[4];
    // d_in[5] = Wss  -- dead path
    const float* Wsv   = (const float*)d_in[6];
    // d_in[7] = Wvv  -- dead path
    const float* W2    = (const float*)d_in[8];

    float* ws    = (float*)d_ws;
    float* D     = ws;             // 18432 f32
    float* M     = ws + 18432;     // 16384 f32
    float* bv    = ws + 34816;     // 128 f32
    unsigned* cnt = (unsigned*)(ws + 34944);  // barrier counter
    float* outp  = (float*)d_out;

    // reset barrier counter every launch (captured as a graph memset node)
    hipMemsetAsync(cnt, 0, sizeof(unsigned), stream);

    fused_mace<<<dim3(256), dim3(256), 0, stream>>>(
        feat, times, Wt, W1s, W1v, Wsv, W2, D, M, bv, cnt, outp);
}

// Round 7
// 22.775 us; speedup vs baseline: 3.1180x; 3.1180x over previous
//
#include <hip/hip_runtime.h>
#include <math.h>

// MACE equivariant score head, restructured (3 kernels).
// Dead code: Wss (d_in[5]), Wvv (d_in[7]) — s3=silu(s2) is deleted in the reference.
// out[n,m] = sum_c vraw[n,c,m] * h[n,c]
// h[n,c]   = t[n]*b[c] + sum_q feat[n,q] * M[q,c]
// Precompute:
//   D[u,v] = dot(Wsv[u,v,:], W2)
//   F[v]   = sum_u wrow[u] * D[u,v]        (wrow = W1s row 16+q, or Wt-combo for b)
//   M[q,c] = scale * sum_v F[v] * W1v[c,v]
//   scale  = 1/(S*V*sqrt(V))  (all fan-in norms folded)

#define S 144
#define V 128

// ---------------- K1: D[uv] = dot(Wsv[uv,:], W2), 18 rows/wave ----------------
// 256 blocks x 4 waves x 18 rows = 18432. Row-pairs: lanes 0-31 row 2i,
// lanes 32-63 row 2i+1, float4 per lane, width-32 butterfly.
__global__ __launch_bounds__(256) void k1_D(const float* __restrict__ Wsv,
                                            const float* __restrict__ W2,
                                            float* __restrict__ D) {
    const int wave = threadIdx.x >> 6;
    const int lane = threadIdx.x & 63;
    const int half = lane >> 5;          // 0 or 1
    const int j = lane & 31;             // float4 index within row
    const int uv0 = blockIdx.x * 72 + wave * 18;

    const float4* Wsv4 = (const float4*)Wsv;   // row stride = 32 float4
    const float4 w4 = ((const float4*)W2)[j];

    float4 a[9];
#pragma unroll
    for (int i = 0; i < 9; ++i)
        a[i] = Wsv4[(size_t)(uv0 + 2 * i + half) * 32 + j];

#pragma unroll
    for (int i = 0; i < 9; ++i) {
        float acc = a[i].x * w4.x + a[i].y * w4.y + a[i].z * w4.z + a[i].w * w4.w;
#pragma unroll
        for (int off = 1; off < 32; off <<= 1)
            acc += __shfl_xor(acc, off, 64);   // stays within 32-lane half
        if (j == 0) D[uv0 + 2 * i + half] = acc;
    }
}

// ---------------- K23: per-block row of M (or b) ----------------
// block q in [0,129): q<128 -> M row q; q==128 -> b.
// W1v staged in LDS (multi-use, padded); D read directly from L2 (single-use).
__global__ __launch_bounds__(256) void k23_Mb(const float* __restrict__ D,
                                              const float* __restrict__ W1s,
                                              const float* __restrict__ W1v,
                                              const float* __restrict__ Wt,
                                              float* __restrict__ M,
                                              float* __restrict__ b) {
    __shared__ float w1v[V * 129];     // 66 KB, +1 pad
    __shared__ float wrow[S];
    __shared__ float Fpart[4][V];
    __shared__ float Fsh[V];
    const int tid = threadIdx.x;
    const int q = blockIdx.x;

    // stage W1v padded: float4 global loads, scalar LDS stores
    {
        const float4* W1v4 = (const float4*)W1v;
        for (int i = tid; i < V * V / 4; i += 256) {
            const float4 t = W1v4[i];
            const int base = i * 4;
            float* dst = &w1v[(base >> 7) * 129 + (base & 127)];
            dst[0] = t.x; dst[1] = t.y; dst[2] = t.z; dst[3] = t.w;
        }
    }
    if (tid < S) {
        if (q < V) {
            wrow[tid] = W1s[(16 + q) * S + tid];
        } else {
            float acc = 0.f;
#pragma unroll
            for (int p = 0; p < 16; ++p)
                acc = fmaf(Wt[p], W1s[p * S + tid], acc);
            wrow[tid] = acc;
        }
    }
    __syncthreads();

    // F[v] = sum_u wrow[u]*D[u,v]; wave w covers u in [36w,36w+36), lane t -> v=2t,2t+1
    {
        const int w = tid >> 6, t = tid & 63;
        float fx = 0.f, fy = 0.f;
#pragma unroll 6
        for (int u = 36 * w; u < 36 * w + 36; ++u) {
            const float wr = wrow[u];
            const float2 dv = *(const float2*)&D[u * V + 2 * t];
            fx = fmaf(wr, dv.x, fx);
            fy = fmaf(wr, dv.y, fy);
        }
        Fpart[w][2 * t + 0] = fx;
        Fpart[w][2 * t + 1] = fy;
    }
    __syncthreads();
    if (tid < V)
        Fsh[tid] = (Fpart[0][tid] + Fpart[1][tid]) + (Fpart[2][tid] + Fpart[3][tid]);
    __syncthreads();

    // out[c] = scale * sum_v Fsh[v] * W1v[c,v],  c = tid (<128)
    if (tid < V) {
        const float scale = 1.0f / (144.0f * 128.0f * sqrtf(128.0f));
        float m0 = 0.f, m1 = 0.f, m2 = 0.f, m3 = 0.f;
#pragma unroll 8
        for (int v = 0; v < V; v += 4) {
            m0 = fmaf(Fsh[v + 0], w1v[tid * 129 + v + 0], m0);
            m1 = fmaf(Fsh[v + 1], w1v[tid * 129 + v + 1], m1);
            m2 = fmaf(Fsh[v + 2], w1v[tid * 129 + v + 2], m2);
            m3 = fmaf(Fsh[v + 3], w1v[tid * 129 + v + 3], m3);
        }
        const float r = ((m0 + m1) + (m2 + m3)) * scale;
        if (q < V) M[q * V + tid] = r;
        else       b[tid] = r;
    }
}

// ---------------- K4: main streaming kernel ----------------
// 512 blocks x 256 thr (4 waves), 8 rows/block, 2 rows/wave.
// LDS = Msh 64KB + srow 4KB = 68KB -> 2 blocks/CU, 8 waves/CU.
__global__ __launch_bounds__(256) void k4_main(const float* __restrict__ feat,
                                               const float* __restrict__ times,
                                               const float* __restrict__ Mg,
                                               const float* __restrict__ bg,
                                               float* __restrict__ out) {
    __shared__ float Msh[V * V];          // 64 KB
    __shared__ float srow[4][2][V];       // 4 KB
    const int tid = threadIdx.x;
    const int wave = tid >> 6;
    const int lane = tid & 63;
    const int n0 = blockIdx.x * 8 + wave * 2;

    // vector part of this wave's 2 rows -> registers (lane owns channels 2l, 2l+1)
    float2 va[2][3];
#pragma unroll
    for (int r = 0; r < 2; ++r) {
        const float* p = feat + (size_t)(n0 + r) * 512 + V + 6 * lane;
        va[r][0] = *(const float2*)(p + 0);
        va[r][1] = *(const float2*)(p + 2);
        va[r][2] = *(const float2*)(p + 4);
    }
    // scalar part -> LDS (broadcast source for the GEMV)
#pragma unroll
    for (int r = 0; r < 2; ++r) {
        float2 sv = *(const float2*)(feat + (size_t)(n0 + r) * 512 + 2 * lane);
        *(float2*)&srow[wave][r][2 * lane] = sv;
    }
    // cooperative M load: 16384 f32 = 4096 float4 / 256 thr
    {
        const float4* src = (const float4*)Mg;
        float4* dst = (float4*)Msh;
#pragma unroll
        for (int i = 0; i < 16; ++i)
            dst[tid + 256 * i] = src[tid + 256 * i];
    }
    const float2 b2 = *(const float2*)(bg + 2 * lane);
    float h0[2], h1[2];
#pragma unroll
    for (int r = 0; r < 2; ++r) {
        const float t = times[n0 + r];
        h0[r] = t * b2.x;
        h1[r] = t * b2.y;
    }
    __syncthreads();

    // h[r, 2l / 2l+1] += sum_q srow[r][q] * M[q, 2l / 2l+1]
#pragma unroll 4
    for (int q4 = 0; q4 < V / 4; ++q4) {
        const float4 s0 = *(const float4*)&srow[wave][0][q4 * 4];
        const float4 s1 = *(const float4*)&srow[wave][1][q4 * 4];
        const float se[2][4] = {{s0.x, s0.y, s0.z, s0.w},
                                {s1.x, s1.y, s1.z, s1.w}};
#pragma unroll
        for (int j = 0; j < 4; ++j) {
            const float2 m2 = *(const float2*)&Msh[(q4 * 4 + j) * V + 2 * lane];
#pragma unroll
            for (int r = 0; r < 2; ++r) {
                h0[r] = fmaf(se[r][j], m2.x, h0[r]);
                h1[r] = fmaf(se[r][j], m2.y, h1[r]);
            }
        }
    }

    // epilogue: lane l holds channels c=2l (va[0].x, va[0].y, va[1].x)
    // and c=2l+1 (va[1].y, va[2].x, va[2].y)
#pragma unroll
    for (int r = 0; r < 2; ++r) {
        float pm0 = va[r][0].x * h0[r] + va[r][1].y * h1[r];
        float pm1 = va[r][0].y * h0[r] + va[r][2].x * h1[r];
        float pm2 = va[r][1].x * h0[r] + va[r][2].y * h1[r];
#pragma unroll
        for (int off = 1; off < 64; off <<= 1) {
            pm0 += __shfl_xor(pm0, off, 64);
            pm1 += __shfl_xor(pm1, off, 64);
            pm2 += __shfl_xor(pm2, off, 64);
        }
        if (lane == 0) {
            out[(n0 + r) * 3 + 0] = pm0;
            out[(n0 + r) * 3 + 1] = pm1;
            out[(n0 + r) * 3 + 2] = pm2;
        }
    }
}

extern "C" void kernel_launch(void* const* d_in, const int* in_sizes, int n_in,
                              void* d_out, int out_size, void* d_ws, size_t ws_size,
                              hipStream_t stream) {
    const float* feat  = (const float*)d_in[0];  // [4096, 512]
    const float* times = (const float*)d_in[1];  // [4096, 1]
    const float* Wt    = (const float*)d_in[2];  // [1,16]
    const float* W1s   = (const float*)d_in[3];  // [144,144]
    const float* W1v   = (const float*)d_in[4];  // [128,128]
    // d_in[5] = Wss  -- dead path
    const float* Wsv   = (const float*)d_in[6];  // [144,128,128]
    // d_in[7] = Wvv  -- dead path
    const float* W2    = (const float*)d_in[8];  // [128,1]

    float* ws = (float*)d_ws;
    float* D  = ws;            // 18432 f32
    float* M  = ws + 18432;    // 16384 f32
    float* b  = ws + 34816;    // 128 f32

    k1_D<<<dim3(256), dim3(256), 0, stream>>>(Wsv, W2, D);
    k23_Mb<<<dim3(129), dim3(256), 0, stream>>>(D, W1s, W1v, Wt, M, b);
    k4_main<<<dim3(512), dim3(256), 0, stream>>>(feat, times, M, b, (float*)d_out);
}